// Round 1
// baseline (1498.389 us; speedup 1.0000x reference)
//
#include <hip/hip_runtime.h>
#include <stdint.h>

#define WIN 14
#define HW 196
#define NH 12
#define HIDDEN 768
#define BH 3072
#define MTOT 50176
#define KDIM 768

typedef __bf16 bf16x8 __attribute__((ext_vector_type(8)));
typedef float f32x4 __attribute__((ext_vector_type(4)));

__device__ __forceinline__ float bf2f(uint16_t u) {
  union { uint32_t i; float f; } v; v.i = ((uint32_t)u) << 16; return v.f;
}
__device__ __forceinline__ uint16_t f2bf(float f) {
  uint32_t u = __float_as_uint(f);
  uint32_t r = u + 0x7FFFu + ((u >> 16) & 1u);
  return (uint16_t)(r >> 16);
}
__device__ __forceinline__ f32x4 mfma16(bf16x8 a, bf16x8 b, f32x4 c) {
  return __builtin_amdgcn_mfma_f32_16x16x32_bf16(a, b, c, 0, 0, 0);
}
__device__ __forceinline__ f32x4 f4zero() { f32x4 z = {0.f, 0.f, 0.f, 0.f}; return z; }

__device__ __forceinline__ void async16(const void* g, void* l) {
#if __has_builtin(__builtin_amdgcn_global_load_lds)
  __builtin_amdgcn_global_load_lds((__attribute__((address_space(1))) void*)g,
                                   (__attribute__((address_space(3))) void*)l, 16, 0, 0);
#else
  *(uint4*)l = *(const uint4*)g;
#endif
}

// ---------------- fp32 -> bf16 convert ----------------
__global__ __launch_bounds__(256) void cvt_bf16(const float* __restrict__ in,
                                                uint16_t* __restrict__ out, int n4) {
  int i = blockIdx.x * blockDim.x + threadIdx.x;
  const int stride = gridDim.x * blockDim.x;
  for (; i < n4; i += stride) {
    float4 v = ((const float4*)in)[i];
    ushort4 o;
    o.x = f2bf(v.x); o.y = f2bf(v.y); o.z = f2bf(v.z); o.w = f2bf(v.w);
    ((ushort4*)out)[i] = o;
  }
}

// ---------------- GEMM: C[m][n] = sum_k A[m][k]*B[n][k] (+bias), bf16 in, K=768 ----
// EPI 0: scatter qkv bf16 (q pre-scaled by 0.125); EPI 1: fp32 out row-major.
template <int EPI>
__global__ __launch_bounds__(256) void gemm_bt(const uint16_t* __restrict__ A,
                                               const uint16_t* __restrict__ B,
                                               const float* __restrict__ bias,
                                               void* __restrict__ outp) {
  __shared__ __align__(16) uint16_t As[128 * 64];
  __shared__ __align__(16) uint16_t Bs[128 * 64];
  const int tid = threadIdx.x;
  const int tile_n = blockIdx.x * 128;
  const int tile_m = blockIdx.y * 128;
  const int wave = tid >> 6, lane = tid & 63;
  const int l15 = lane & 15, quad = lane >> 4;
  const int wm = (wave & 1) * 64, wn = (wave >> 1) * 64;

  f32x4 acc[4][4];
#pragma unroll
  for (int mi = 0; mi < 4; mi++)
#pragma unroll
    for (int ni = 0; ni < 4; ni++) acc[mi][ni] = f4zero();

  for (int k0 = 0; k0 < KDIM; k0 += 64) {
    // XOR-swizzled staging: chunk (r,c) lives at lds r*128 + (c^(r&7))*16
#pragma unroll
    for (int i = 0; i < 4; i++) {
      const int o = tid * 16 + i * 4096;
      const int r = o >> 7;
      const int c = ((o >> 4) & 7) ^ (r & 7);
      async16((const uint8_t*)A + ((size_t)(tile_m + r) * KDIM + k0 + c * 8) * 2,
              (uint8_t*)As + o);
    }
#pragma unroll
    for (int i = 0; i < 4; i++) {
      const int o = tid * 16 + i * 4096;
      const int r = o >> 7;
      const int c = ((o >> 4) & 7) ^ (r & 7);
      async16((const uint8_t*)B + ((size_t)(tile_n + r) * KDIM + k0 + c * 8) * 2,
              (uint8_t*)Bs + o);
    }
    __syncthreads();
#pragma unroll
    for (int kk = 0; kk < 2; kk++) {
      bf16x8 af[4], bfr[4];
#pragma unroll
      for (int mi = 0; mi < 4; mi++) {
        const int r = wm + mi * 16 + l15;
        const int c = (kk * 4 + quad) ^ (r & 7);
        af[mi] = *(const bf16x8*)(As + r * 64 + c * 8);
      }
#pragma unroll
      for (int ni = 0; ni < 4; ni++) {
        const int r = wn + ni * 16 + l15;
        const int c = (kk * 4 + quad) ^ (r & 7);
        bfr[ni] = *(const bf16x8*)(Bs + r * 64 + c * 8);
      }
#pragma unroll
      for (int mi = 0; mi < 4; mi++)
#pragma unroll
        for (int ni = 0; ni < 4; ni++)
          acc[mi][ni] = mfma16(af[mi], bfr[ni], acc[mi][ni]);
    }
    __syncthreads();
  }

#pragma unroll
  for (int mi = 0; mi < 4; mi++) {
#pragma unroll
    for (int ni = 0; ni < 4; ni++) {
#pragma unroll
      for (int rg = 0; rg < 4; rg++) {
        const int m = tile_m + wm + mi * 16 + quad * 4 + rg;
        const int n = tile_n + wn + ni * 16 + l15;
        float v = acc[mi][ni][rg] + bias[n];
        if (EPI == 0) {
          const int which = n / HIDDEN;
          const int rem = n - which * HIDDEN;
          const int head = rem >> 6, d = rem & 63;
          const int b = m / HW;
          const int s = m - b * HW;
          if (which == 0) v *= 0.125f;  // q pre-scaled by hd^-0.5
          ((uint16_t*)outp)[(((size_t)which * BH + (size_t)b * NH + head) * HW + s) * 64 + d] =
              f2bf(v);
        } else {
          ((float*)outp)[(size_t)m * HIDDEN + n] = v;
        }
      }
    }
  }
}

// ---------------- rel-pos bias: out[bh][s][p] p<14: q.Rh[h-p+13]*8 ; p>=14: q.Rw ----
__global__ __launch_bounds__(256) void rel_kernel(const uint16_t* __restrict__ qkv,
                                                  const float* __restrict__ Rh,
                                                  const float* __restrict__ Rw,
                                                  float* __restrict__ out) {
  const int bh = blockIdx.x;
  const uint16_t* q = qkv + (size_t)bh * HW * 64;
  float* ob = out + (size_t)bh * HW * 28;
  for (int task = threadIdx.x; task < HW * 28; task += 256) {
    const int s = task / 28, p = task - s * 28;
    const int h = s / WIN, w = s - h * WIN;
    const int kk = (p < 14) ? p : (p - 14);
    const int idx = ((p < 14) ? h : w) - kk + 13;
    const float* R = ((p < 14) ? Rh : Rw) + idx * 64;
    const uint16_t* qr = q + s * 64;
    float sum = 0.f;
#pragma unroll
    for (int c = 0; c < 8; c++) {
      uint4 qv = *(const uint4*)(qr + c * 8);
      const uint16_t* qe = (const uint16_t*)&qv;
      float4 r0 = *(const float4*)(R + c * 8);
      float4 r1 = *(const float4*)(R + c * 8 + 4);
      sum += bf2f(qe[0]) * r0.x + bf2f(qe[1]) * r0.y + bf2f(qe[2]) * r0.z + bf2f(qe[3]) * r0.w +
             bf2f(qe[4]) * r1.x + bf2f(qe[5]) * r1.y + bf2f(qe[6]) * r1.z + bf2f(qe[7]) * r1.w;
    }
    ob[task] = sum * 8.0f;  // undo q pre-scale: bias uses unscaled q
  }
}

// ---------------- fused attention: one block = (bh, 64-row q tile) ----------------
__global__ __launch_bounds__(256) void attn_kernel(const uint16_t* __restrict__ qkv,
                                                   const float* __restrict__ relb,
                                                   uint16_t* __restrict__ aout) {
  __shared__ __align__(16) uint8_t smem[64768];
  uint16_t* Ks = (uint16_t*)smem;             // [208][72] (pad rows/cols; garbage ok, masked)
  uint16_t* Vt = (uint16_t*)smem;             // [64][232] (union with Ks after barrier)
  uint16_t* Qs = (uint16_t*)(smem + 29952);   // [64][64]
  uint16_t* Ps = (uint16_t*)(smem + 38144);   // [64][208]

  const int qt = blockIdx.x;  // 0..3
  const int bh = blockIdx.y;  // 0..3071
  const int q0 = qt * 64;
  const int tid = threadIdx.x;
  const int wave = tid >> 6, lane = tid & 63;
  const int l15 = lane & 15, quad = lane >> 4;

  const uint16_t* qg = qkv + (size_t)bh * HW * 64;
  const uint16_t* kg = qkv + ((size_t)BH + bh) * HW * 64;
  const uint16_t* vg = qkv + ((size_t)2 * BH + bh) * HW * 64;

  // stage Q tile (zero-padded rows) and K
#pragma unroll
  for (int i = 0; i < 2; i++) {
    const int c = tid + i * 256;
    const int r = c >> 3, cb = (c & 7) * 8;
    uint4 v = make_uint4(0u, 0u, 0u, 0u);
    if (q0 + r < HW) v = *(const uint4*)(qg + (size_t)(q0 + r) * 64 + cb);
    *(uint4*)(Qs + r * 64 + cb) = v;
  }
#pragma unroll
  for (int i = 0; i < 7; i++) {
    const int c = tid + i * 256;
    if (c < 1568) {
      const int r = c >> 3, cb = (c & 7) * 8;
      uint4 v = *(const uint4*)(kg + (size_t)r * 64 + cb);
      *(uint4*)(Ks + r * 72 + cb) = v;
    }
  }
  __syncthreads();

  // prefetch V into registers (latency hidden under S-phase MFMAs)
  uint4 vreg[7];
#pragma unroll
  for (int i = 0; i < 7; i++) {
    const int c = tid + i * 256;
    if (c < 1568) vreg[i] = *(const uint4*)(vg + (size_t)c * 8);
  }

  // S = Q*K^T : 13 col tiles of 16, accumulators in registers (C layout)
  f32x4 sacc[13];
#pragma unroll
  for (int nt = 0; nt < 13; nt++) sacc[nt] = f4zero();
  {
    const int arow = wave * 16 + l15;
    bf16x8 a0 = *(const bf16x8*)(Qs + arow * 64 + quad * 8);
    bf16x8 a1 = *(const bf16x8*)(Qs + arow * 64 + 32 + quad * 8);
#pragma unroll
    for (int nt = 0; nt < 13; nt++) {
      const int br = nt * 16 + l15;
      bf16x8 b0 = *(const bf16x8*)(Ks + br * 72 + quad * 8);
      bf16x8 b1 = *(const bf16x8*)(Ks + br * 72 + 32 + quad * 8);
      sacc[nt] = mfma16(a0, b0, sacc[nt]);
      sacc[nt] = mfma16(a1, b1, sacc[nt]);
    }
  }
  __syncthreads();  // all waves done with Ks; V loads drained

  // write V^T over the Ks region
#pragma unroll
  for (int i = 0; i < 7; i++) {
    const int c = tid + i * 256;
    if (c < 1568) {
      const int j = c >> 3, d0 = (c & 7) * 8;
      const uint16_t* pe = (const uint16_t*)&vreg[i];
#pragma unroll
      for (int e = 0; e < 8; e++) Vt[(d0 + e) * 232 + j] = pe[e];
    }
  }
  for (int idx = tid; idx < 64 * 12; idx += 256) {  // zero j=196..207 (finite for MFMA)
    const int d = idx / 12, j = HW + (idx - d * 12);
    Vt[d * 232 + j] = 0;
  }

  // bias + softmax in registers; P -> LDS (A-operand layout)
  {
    const float* rb = relb + (size_t)bh * HW * 28;
#pragma unroll
    for (int rg = 0; rg < 4; rg++) {
      const int lrow = wave * 16 + quad * 4 + rg;
      const int qrow = q0 + lrow;
      const int qr = (qrow < HW) ? qrow : (HW - 1);
      const float* rbr = rb + (size_t)qr * 28;
      float vals[13];
      float mx = -1e30f;
#pragma unroll
      for (int nt = 0; nt < 13; nt++) {
        const int col = nt * 16 + l15;
        float s = sacc[nt][rg];
        if (col < HW) {
          const int kh = col / WIN;
          const int kw = col - kh * WIN;
          s += rbr[kh] + rbr[14 + kw];
        } else {
          s = -1e30f;
        }
        vals[nt] = s;
        mx = fmaxf(mx, s);
      }
#pragma unroll
      for (int off = 1; off < 16; off <<= 1) mx = fmaxf(mx, __shfl_xor(mx, off, 64));
      float sum = 0.f;
#pragma unroll
      for (int nt = 0; nt < 13; nt++) {
        const float p = __expf(vals[nt] - mx);
        vals[nt] = p;
        sum += p;
      }
#pragma unroll
      for (int off = 1; off < 16; off <<= 1) sum += __shfl_xor(sum, off, 64);
      const float inv = 1.f / sum;
#pragma unroll
      for (int nt = 0; nt < 13; nt++) Ps[lrow * 208 + nt * 16 + l15] = f2bf(vals[nt] * inv);
    }
  }
  __syncthreads();

  // O = P*V : 4 d-tiles, K-dim 208 in 7 mfma steps (tail quads zeroed)
  f32x4 oacc[4];
#pragma unroll
  for (int nt = 0; nt < 4; nt++) oacc[nt] = f4zero();
  {
    const int arow = wave * 16 + l15;
#pragma unroll
    for (int ks = 0; ks < 7; ks++) {
      const int k = ks * 32 + quad * 8;
      bf16x8 af;
      if (k < 208) {
        af = *(const bf16x8*)(Ps + arow * 208 + k);
      } else {
        uint4 z = make_uint4(0u, 0u, 0u, 0u);
        af = __builtin_bit_cast(bf16x8, z);
      }
      const int kb = (k < 208) ? k : 0;
#pragma unroll
      for (int nt = 0; nt < 4; nt++) {
        bf16x8 bv = *(const bf16x8*)(Vt + (nt * 16 + l15) * 232 + kb);
        oacc[nt] = mfma16(af, bv, oacc[nt]);
      }
    }
  }

  const int b = bh / NH, head = bh - b * NH;
#pragma unroll
  for (int nt = 0; nt < 4; nt++) {
#pragma unroll
    for (int rg = 0; rg < 4; rg++) {
      const int qrow = q0 + wave * 16 + quad * 4 + rg;
      if (qrow < HW) {
        const int d = nt * 16 + l15;
        aout[((size_t)b * HW + qrow) * HIDDEN + head * 64 + d] = f2bf(oacc[nt][rg]);
      }
    }
  }
}

extern "C" void kernel_launch(void* const* d_in, const int* in_sizes, int n_in,
                              void* d_out, int out_size, void* d_ws, size_t ws_size,
                              hipStream_t stream) {
  const float* hidden = (const float*)d_in[0];
  const float* qkv_w = (const float*)d_in[1];
  const float* qkv_b = (const float*)d_in[2];
  const float* proj_w = (const float*)d_in[3];
  const float* proj_b = (const float*)d_in[4];
  const float* rel_h = (const float*)d_in[5];
  const float* rel_w = (const float*)d_in[6];

  uint8_t* ws = (uint8_t*)d_ws;
  uint16_t* Xb = (uint16_t*)(ws);                  // 77,070,336 B; reused as attn_out
  uint16_t* qkvb = (uint16_t*)(ws + 77070336);     // 231,211,008 B: [3][3072][196][64] bf16
  float* relb = (float*)(ws + 308281344);          // 67,436,544 B: [3072][196][28] f32
  uint16_t* wqkvb = (uint16_t*)(ws + 375717888);   // 3,538,944 B
  uint16_t* wprjb = (uint16_t*)(ws + 379256832);   // 1,179,648 B

  cvt_bf16<<<4096, 256, 0, stream>>>(hidden, Xb, (MTOT * HIDDEN) / 4);
  cvt_bf16<<<1024, 256, 0, stream>>>(qkv_w, wqkvb, (3 * HIDDEN * HIDDEN) / 4);
  cvt_bf16<<<576, 256, 0, stream>>>(proj_w, wprjb, (HIDDEN * HIDDEN) / 4);

  gemm_bt<0><<<dim3(18, 392), 256, 0, stream>>>(Xb, wqkvb, qkv_b, (void*)qkvb);
  rel_kernel<<<BH, 256, 0, stream>>>(qkvb, rel_h, rel_w, relb);
  attn_kernel<<<dim3(4, BH), 256, 0, stream>>>(qkvb, relb, Xb);
  gemm_bt<1><<<dim3(6, 392), 256, 0, stream>>>(Xb, wprjb, proj_b, d_out);
}

// Round 2
// 982.717 us; speedup vs baseline: 1.5247x; 1.5247x over previous
//
#include <hip/hip_runtime.h>
#include <stdint.h>

#define WIN 14
#define HW 196
#define NH 12
#define HIDDEN 768
#define BH 3072
#define MTOT 50176
#define KDIM 768

typedef __bf16 bf16x8 __attribute__((ext_vector_type(8)));
typedef float f32x4 __attribute__((ext_vector_type(4)));

__device__ __forceinline__ float bf2f(uint16_t u) {
  union { uint32_t i; float f; } v; v.i = ((uint32_t)u) << 16; return v.f;
}
__device__ __forceinline__ uint16_t f2bf(float f) {
  uint32_t u = __float_as_uint(f);
  uint32_t r = u + 0x7FFFu + ((u >> 16) & 1u);
  return (uint16_t)(r >> 16);
}
__device__ __forceinline__ f32x4 mfma16(bf16x8 a, bf16x8 b, f32x4 c) {
  return __builtin_amdgcn_mfma_f32_16x16x32_bf16(a, b, c, 0, 0, 0);
}
__device__ __forceinline__ f32x4 f4zero() { f32x4 z = {0.f, 0.f, 0.f, 0.f}; return z; }

__device__ __forceinline__ void async16(const void* g, void* l) {
#if __has_builtin(__builtin_amdgcn_global_load_lds)
  __builtin_amdgcn_global_load_lds((__attribute__((address_space(1))) void*)g,
                                   (__attribute__((address_space(3))) void*)l, 16, 0, 0);
#else
  *(uint4*)l = *(const uint4*)g;
#endif
}

// ---------------- fp32 -> bf16 convert ----------------
__global__ __launch_bounds__(256) void cvt_bf16(const float* __restrict__ in,
                                                uint16_t* __restrict__ out, int n4) {
  int i = blockIdx.x * blockDim.x + threadIdx.x;
  const int stride = gridDim.x * blockDim.x;
  for (; i < n4; i += stride) {
    float4 v = ((const float4*)in)[i];
    ushort4 o;
    o.x = f2bf(v.x); o.y = f2bf(v.y); o.z = f2bf(v.z); o.w = f2bf(v.w);
    ((ushort4*)out)[i] = o;
  }
}

// ---------------- build rel-pos B-operand table: Rt[64][64] bf16 ----------------
// rows 0..26 = rel_pos_h * 8, rows 32..58 = rel_pos_w * 8, rest zero.
__global__ __launch_bounds__(256) void build_rt(const float* __restrict__ rh,
                                                const float* __restrict__ rw,
                                                uint16_t* __restrict__ Rt) {
  const int i = blockIdx.x * 256 + threadIdx.x;
  if (i < 4096) {
    const int r = i >> 6, c = i & 63;
    float v = 0.f;
    if (r < 27) v = rh[r * 64 + c] * 8.f;
    else if (r >= 32 && r < 59) v = rw[(r - 32) * 64 + c] * 8.f;
    Rt[i] = f2bf(v);
  }
}

// ---------------- GEMM: C[m][n] = sum_k A[m][k]*B[n][k] (+bias), bf16 in, K=768 ----
// EPI 0: scatter qkv bf16 (q pre-scaled by 0.125); EPI 1: fp32 out row-major.
template <int EPI>
__global__ __launch_bounds__(256) void gemm_bt(const uint16_t* __restrict__ A,
                                               const uint16_t* __restrict__ B,
                                               const float* __restrict__ bias,
                                               void* __restrict__ outp) {
  __shared__ __align__(16) uint16_t As[128 * 64];
  __shared__ __align__(16) uint16_t Bs[128 * 64];
  const int tid = threadIdx.x;
  const int tile_n = blockIdx.x * 128;
  const int tile_m = blockIdx.y * 128;
  const int wave = tid >> 6, lane = tid & 63;
  const int l15 = lane & 15, quad = lane >> 4;
  const int wm = (wave & 1) * 64, wn = (wave >> 1) * 64;

  f32x4 acc[4][4];
#pragma unroll
  for (int mi = 0; mi < 4; mi++)
#pragma unroll
    for (int ni = 0; ni < 4; ni++) acc[mi][ni] = f4zero();

  for (int k0 = 0; k0 < KDIM; k0 += 64) {
    // XOR-swizzled staging: chunk (r,c) lives at lds r*128 + (c^(r&7))*16
#pragma unroll
    for (int i = 0; i < 4; i++) {
      const int o = tid * 16 + i * 4096;
      const int r = o >> 7;
      const int c = ((o >> 4) & 7) ^ (r & 7);
      async16((const uint8_t*)A + ((size_t)(tile_m + r) * KDIM + k0 + c * 8) * 2,
              (uint8_t*)As + o);
    }
#pragma unroll
    for (int i = 0; i < 4; i++) {
      const int o = tid * 16 + i * 4096;
      const int r = o >> 7;
      const int c = ((o >> 4) & 7) ^ (r & 7);
      async16((const uint8_t*)B + ((size_t)(tile_n + r) * KDIM + k0 + c * 8) * 2,
              (uint8_t*)Bs + o);
    }
    __syncthreads();
#pragma unroll
    for (int kk = 0; kk < 2; kk++) {
      bf16x8 af[4], bfr[4];
#pragma unroll
      for (int mi = 0; mi < 4; mi++) {
        const int r = wm + mi * 16 + l15;
        const int c = (kk * 4 + quad) ^ (r & 7);
        af[mi] = *(const bf16x8*)(As + r * 64 + c * 8);
      }
#pragma unroll
      for (int ni = 0; ni < 4; ni++) {
        const int r = wn + ni * 16 + l15;
        const int c = (kk * 4 + quad) ^ (r & 7);
        bfr[ni] = *(const bf16x8*)(Bs + r * 64 + c * 8);
      }
#pragma unroll
      for (int mi = 0; mi < 4; mi++)
#pragma unroll
        for (int ni = 0; ni < 4; ni++)
          acc[mi][ni] = mfma16(af[mi], bfr[ni], acc[mi][ni]);
    }
    __syncthreads();
  }

#pragma unroll
  for (int mi = 0; mi < 4; mi++) {
#pragma unroll
    for (int ni = 0; ni < 4; ni++) {
#pragma unroll
      for (int rg = 0; rg < 4; rg++) {
        const int m = tile_m + wm + mi * 16 + quad * 4 + rg;
        const int n = tile_n + wn + ni * 16 + l15;
        float v = acc[mi][ni][rg] + bias[n];
        if (EPI == 0) {
          const int which = n / HIDDEN;
          const int rem = n - which * HIDDEN;
          const int head = rem >> 6, d = rem & 63;
          const int b = m / HW;
          const int s = m - b * HW;
          if (which == 0) v *= 0.125f;  // q pre-scaled by hd^-0.5
          ((uint16_t*)outp)[(((size_t)which * BH + (size_t)b * NH + head) * HW + s) * 64 + d] =
              f2bf(v);
        } else {
          ((float*)outp)[(size_t)m * HIDDEN + n] = v;
        }
      }
    }
  }
}

// ---------------- fused attention: one block = (bh, 64-row q tile) ----------------
// Rel-pos bias computed in-kernel: T = Q_tile @ Rt^T via MFMA (Rt rows 0..26 = Rh*8,
// 32..58 = Rw*8), staged bf16 into the dead Qs LDS region, gathered during softmax.
__global__ __launch_bounds__(256) void attn_kernel(const uint16_t* __restrict__ qkv,
                                                   const uint16_t* __restrict__ Rt,
                                                   uint16_t* __restrict__ aout) {
  __shared__ __align__(16) uint8_t smem[64768];
  uint16_t* Ks = (uint16_t*)smem;             // [208][72] (pad rows/cols; garbage ok, masked)
  uint16_t* Vt = (uint16_t*)smem;             // [64][232] (union with Ks after barrier)
  uint16_t* Qs = (uint16_t*)(smem + 29952);   // [64][64]
  uint16_t* Ts = (uint16_t*)(smem + 29952);   // bf16 [64][64] rel-bias T, overlays Qs
  uint16_t* Ps = (uint16_t*)(smem + 38144);   // [64][208]

  const int qt = blockIdx.x;  // 0..3
  const int bh = blockIdx.y;  // 0..3071
  const int q0 = qt * 64;
  const int tid = threadIdx.x;
  const int wave = tid >> 6, lane = tid & 63;
  const int l15 = lane & 15, quad = lane >> 4;

  const uint16_t* qg = qkv + (size_t)bh * HW * 64;
  const uint16_t* kg = qkv + ((size_t)BH + bh) * HW * 64;
  const uint16_t* vg = qkv + ((size_t)2 * BH + bh) * HW * 64;

  // stage Q tile (zero-padded rows) and K
#pragma unroll
  for (int i = 0; i < 2; i++) {
    const int c = tid + i * 256;
    const int r = c >> 3, cb = (c & 7) * 8;
    uint4 v = make_uint4(0u, 0u, 0u, 0u);
    if (q0 + r < HW) v = *(const uint4*)(qg + (size_t)(q0 + r) * 64 + cb);
    *(uint4*)(Qs + r * 64 + cb) = v;
  }
#pragma unroll
  for (int i = 0; i < 7; i++) {
    const int c = tid + i * 256;
    if (c < 1568) {
      const int r = c >> 3, cb = (c & 7) * 8;
      uint4 v = *(const uint4*)(kg + (size_t)r * 64 + cb);
      *(uint4*)(Ks + r * 72 + cb) = v;
    }
  }
  __syncthreads();

  // prefetch V into registers (latency hidden under S-phase MFMAs)
  uint4 vreg[7];
#pragma unroll
  for (int i = 0; i < 7; i++) {
    const int c = tid + i * 256;
    if (c < 1568) vreg[i] = *(const uint4*)(vg + (size_t)c * 8);
  }

  // S = Q*K^T : 13 col tiles of 16, accumulators in registers (C layout)
  // + T = Q*Rt^T : 4 col tiles (rel-pos bias), reusing the same A fragments
  f32x4 sacc[13];
  f32x4 racc[4];
#pragma unroll
  for (int nt = 0; nt < 13; nt++) sacc[nt] = f4zero();
#pragma unroll
  for (int nt = 0; nt < 4; nt++) racc[nt] = f4zero();
  {
    const int arow = wave * 16 + l15;
    bf16x8 a0 = *(const bf16x8*)(Qs + arow * 64 + quad * 8);
    bf16x8 a1 = *(const bf16x8*)(Qs + arow * 64 + 32 + quad * 8);
#pragma unroll
    for (int nt = 0; nt < 13; nt++) {
      const int br = nt * 16 + l15;
      bf16x8 b0 = *(const bf16x8*)(Ks + br * 72 + quad * 8);
      bf16x8 b1 = *(const bf16x8*)(Ks + br * 72 + 32 + quad * 8);
      sacc[nt] = mfma16(a0, b0, sacc[nt]);
      sacc[nt] = mfma16(a1, b1, sacc[nt]);
    }
#pragma unroll
    for (int nt = 0; nt < 4; nt++) {
      bf16x8 b0 = *(const bf16x8*)(Rt + (nt * 16 + l15) * 64 + quad * 8);
      bf16x8 b1 = *(const bf16x8*)(Rt + (nt * 16 + l15) * 64 + 32 + quad * 8);
      racc[nt] = mfma16(a0, b0, racc[nt]);
      racc[nt] = mfma16(a1, b1, racc[nt]);
    }
  }
  __syncthreads();  // all waves done with Qs/Ks; V loads drained

  // write T (bf16) over the dead Qs region — each wave owns rows wave*16..+15,
  // and only this wave reads them back (same-wave DS ordering).
#pragma unroll
  for (int nt = 0; nt < 4; nt++) {
#pragma unroll
    for (int rg = 0; rg < 4; rg++) {
      Ts[(wave * 16 + quad * 4 + rg) * 64 + nt * 16 + l15] = f2bf(racc[nt][rg]);
    }
  }

  // write V^T over the Ks region
#pragma unroll
  for (int i = 0; i < 7; i++) {
    const int c = tid + i * 256;
    if (c < 1568) {
      const int j = c >> 3, d0 = (c & 7) * 8;
      const uint16_t* pe = (const uint16_t*)&vreg[i];
#pragma unroll
      for (int e = 0; e < 8; e++) Vt[(d0 + e) * 232 + j] = pe[e];
    }
  }
  for (int idx = tid; idx < 64 * 12; idx += 256) {  // zero j=196..207 (finite for MFMA)
    const int d = idx / 12, j = HW + (idx - d * 12);
    Vt[d * 232 + j] = 0;
  }

  // bias + softmax in registers; P -> LDS (A-operand layout)
  {
#pragma unroll
    for (int rg = 0; rg < 4; rg++) {
      const int lrow = wave * 16 + quad * 4 + rg;
      const int qrow = q0 + lrow;
      const int qr = (qrow < HW) ? qrow : (HW - 1);
      const int hq = qr / WIN, wq = qr - (qr / WIN) * WIN;
      const uint16_t* Tr = Ts + lrow * 64;
      float vals[13];
      float mx = -1e30f;
#pragma unroll
      for (int nt = 0; nt < 13; nt++) {
        const int col = nt * 16 + l15;
        float s = sacc[nt][rg];
        if (col < HW) {
          const int kh = col / WIN;
          const int kw = col - kh * WIN;
          s += bf2f(Tr[hq - kh + 13]) + bf2f(Tr[32 + wq - kw + 13]);
        } else {
          s = -1e30f;
        }
        vals[nt] = s;
        mx = fmaxf(mx, s);
      }
#pragma unroll
      for (int off = 1; off < 16; off <<= 1) mx = fmaxf(mx, __shfl_xor(mx, off, 64));
      float sum = 0.f;
#pragma unroll
      for (int nt = 0; nt < 13; nt++) {
        const float p = __expf(vals[nt] - mx);
        vals[nt] = p;
        sum += p;
      }
#pragma unroll
      for (int off = 1; off < 16; off <<= 1) sum += __shfl_xor(sum, off, 64);
      const float inv = 1.f / sum;
#pragma unroll
      for (int nt = 0; nt < 13; nt++) Ps[lrow * 208 + nt * 16 + l15] = f2bf(vals[nt] * inv);
    }
  }
  __syncthreads();

  // O = P*V : 4 d-tiles, K-dim 208 in 7 mfma steps (tail quads zeroed)
  f32x4 oacc[4];
#pragma unroll
  for (int nt = 0; nt < 4; nt++) oacc[nt] = f4zero();
  {
    const int arow = wave * 16 + l15;
#pragma unroll
    for (int ks = 0; ks < 7; ks++) {
      const int k = ks * 32 + quad * 8;
      bf16x8 af;
      if (k < 208) {
        af = *(const bf16x8*)(Ps + arow * 208 + k);
      } else {
        uint4 z = make_uint4(0u, 0u, 0u, 0u);
        af = __builtin_bit_cast(bf16x8, z);
      }
      const int kb = (k < 208) ? k : 0;
#pragma unroll
      for (int nt = 0; nt < 4; nt++) {
        bf16x8 bv = *(const bf16x8*)(Vt + (nt * 16 + l15) * 232 + kb);
        oacc[nt] = mfma16(af, bv, oacc[nt]);
      }
    }
  }

  const int b = bh / NH, head = bh - b * NH;
#pragma unroll
  for (int nt = 0; nt < 4; nt++) {
#pragma unroll
    for (int rg = 0; rg < 4; rg++) {
      const int qrow = q0 + wave * 16 + quad * 4 + rg;
      if (qrow < HW) {
        const int d = nt * 16 + l15;
        aout[((size_t)b * HW + qrow) * HIDDEN + head * 64 + d] = f2bf(oacc[nt][rg]);
      }
    }
  }
}

extern "C" void kernel_launch(void* const* d_in, const int* in_sizes, int n_in,
                              void* d_out, int out_size, void* d_ws, size_t ws_size,
                              hipStream_t stream) {
  const float* hidden = (const float*)d_in[0];
  const float* qkv_w = (const float*)d_in[1];
  const float* qkv_b = (const float*)d_in[2];
  const float* proj_w = (const float*)d_in[3];
  const float* proj_b = (const float*)d_in[4];
  const float* rel_h = (const float*)d_in[5];
  const float* rel_w = (const float*)d_in[6];

  uint8_t* ws = (uint8_t*)d_ws;
  uint16_t* Xb = (uint16_t*)(ws);                  // 77,070,336 B; reused as attn_out
  uint16_t* qkvb = (uint16_t*)(ws + 77070336);     // 231,211,008 B: [3][3072][196][64] bf16
  uint16_t* Rt = (uint16_t*)(ws + 308281344);      // 8,192 B: [64][64] bf16 rel table
  uint16_t* wqkvb = (uint16_t*)(ws + 308289536);   // 3,538,944 B
  uint16_t* wprjb = (uint16_t*)(ws + 311828480);   // 1,179,648 B

  cvt_bf16<<<4096, 256, 0, stream>>>(hidden, Xb, (MTOT * HIDDEN) / 4);
  cvt_bf16<<<1024, 256, 0, stream>>>(qkv_w, wqkvb, (3 * HIDDEN * HIDDEN) / 4);
  cvt_bf16<<<576, 256, 0, stream>>>(proj_w, wprjb, (HIDDEN * HIDDEN) / 4);
  build_rt<<<16, 256, 0, stream>>>(rel_h, rel_w, Rt);

  gemm_bt<0><<<dim3(18, 392), 256, 0, stream>>>(Xb, wqkvb, qkv_b, (void*)qkvb);
  attn_kernel<<<dim3(4, BH), 256, 0, stream>>>(qkvb, Rt, Xb);
  gemm_bt<1><<<dim3(6, 392), 256, 0, stream>>>(Xb, wprjb, proj_b, d_out);
}